// Round 15
// baseline (69.386 us; speedup 1.0000x reference)
//
#include <hip/hip_runtime.h>
#include <math.h>

// DRR via Siddon ray tracing, 256^3 volume, 256x256 detector.
// Two kernels: (1) ray_setup precomputes per-ray geometry (16 floats/ray into
// d_ws) once -- trig, divides, bounds, premultiplied midpoint coefficients --
// removing ~30% of the main kernel's VALU issue that was duplicated across
// the 16 partition-threads of each ray. (2) drr_kernel: R10's proven skeleton
// (block = 16 consecutive rays lane-fast x 16 alpha-partitions slow, wave =
// 16 rays x 4 adjacent partitions, natural block order, shfl+LDS reduction)
// with the lean inner body: float y/z plane indices without range checks
// (R7/R8/R14-proven), x-cell from the pending plane index (R12-proven),
// y/z cells via midpoint-trunc with premultiplied 1/spacing (bit-identical
// at spacing==1; reference rounding-snap preserved).

#define NPLANE 256
constexpr int TPR = 16;

__device__ __forceinline__ float palpha(int i, float sp, float src, float rd) {
    return fmaf((float)i, sp, -src) * rd;
}
__device__ __forceinline__ float palpha_f(float fi, float sp, float nsrc, float rd) {
    return fmaf(fi, sp, nsrc) * rd;
}

// ---- per-ray geometry precompute: 16 floats per ray into d_ws ----
__global__ __launch_bounds__(256) void ray_setup(
    const float* __restrict__ spacing,
    const float* __restrict__ sdrp,
    const float* __restrict__ rot,
    const float* __restrict__ trans,
    float* __restrict__ ws)
{
    int rl = (int)blockIdx.x * 256 + threadIdx.x;

    float theta = rot[0], phi = rot[1], gam = rot[2];
    float ct = cosf(theta), st = sinf(theta);
    float cp = cosf(phi),   sp_ = sinf(phi);
    float cg = cosf(gam),   sg = sinf(gam);

    float r0x = ct * cp, r0y = st * cp, r0z = -sp_;
    float ux = ct*sp_*sg - st*cg, uy = st*sp_*sg + ct*cg, uz = cp*sg;
    float vx = ct*sp_*cg + st*sg, vy = st*sp_*cg - ct*sg, vz = cp*cg;

    // lane-fast detector axis = least stride-weighted volume motion (uniform)
    float cost_u = fabsf(ux)*65536.f + fabsf(uy)*256.f + fabsf(uz);
    float cost_v = fabsf(vx)*65536.f + fabsf(vy)*256.f + fabsf(vz);
    bool tfast = cost_u < cost_v;
    int ti = tfast ? (rl & 255) : (rl >> 8);
    int si = tfast ? (rl >> 8) : (rl & 255);

    float sdr = sdrp[0];
    float tx = trans[0], ty = trans[1], tz = trans[2];

    float sx = sdr*r0x + tx,  sy = sdr*r0y + ty,  sz = sdr*r0z + tz;
    float cxx = -sdr*r0x + tx, cxy = -sdr*r0y + ty, cxz = -sdr*r0z + tz;

    float tval = (float)(ti - 127) * 2.0f;
    float sval = (float)(si - 127) * 2.0f;

    float gx = tval*ux + sval*vx + cxx;
    float gy = tval*uy + sval*vy + cxy;
    float gz = tval*uz + sval*vz + cxz;

    float sdx = gx - sx + 1e-8f;
    float sdy = gy - sy + 1e-8f;
    float sdz = gz - sz + 1e-8f;

    float spx = spacing[0], spy = spacing[1], spz = spacing[2];
    float rdx = 1.f/sdx, rdy = 1.f/sdy, rdz = 1.f/sdz;

    float a0x = palpha(0,spx,sx,rdx), a1x = palpha(NPLANE,spx,sx,rdx);
    float a0y = palpha(0,spy,sy,rdy), a1y = palpha(NPLANE,spy,sy,rdy);
    float a0z = palpha(0,spz,sz,rdz), a1z = palpha(NPLANE,spz,sz,rdz);

    float amin = fmaxf(fmaxf(fminf(a0x,a1x), fminf(a0y,a1y)), fminf(a0z,a1z));
    float amax = fminf(fminf(fmaxf(a0x,a1x), fmaxf(a0y,a1y)), fmaxf(a0z,a1z));

    float rlen = sqrtf(sdx*sdx + sdy*sdy + sdz*sdz);
    float ispy = 1.f/spy, ispz = 1.f/spz;

    float4* rec = (float4*)(ws + (size_t)rl * 16);
    rec[0] = make_float4(sx, sy, sz, sdx);
    rec[1] = make_float4(sdy, sdz, rdx, rdy);
    rec[2] = make_float4(rdz, amin, amax, rlen);
    rec[3] = make_float4(sdy*ispy, sy*ispy, sdz*ispz, sz*ispz);

    if (rl == 0)
        *(int*)(ws + (size_t)65536 * 16) = tfast ? 1 : 0;
}

__global__ __launch_bounds__(256) void drr_kernel(
    const float* __restrict__ vol,
    const float* __restrict__ spacing,
    const float* __restrict__ ws,
    float* __restrict__ out)
{
    int tid  = threadIdx.x;
    int part = tid >> 4;                       // 0..15 (slow)
    int rlo  = tid & 15;                       // ray-in-block (fast)
    int rl   = ((int)blockIdx.x << 4) | rlo;   // 0..65535 linear ray id

    const float4* rec = (const float4*)(ws + (size_t)rl * 16);
    float4 q0 = rec[0], q1 = rec[1], q2 = rec[2], q3 = rec[3];
    float sx = q0.x,  sy = q0.y,  sz = q0.z,  sdx = q0.w;
    float sdy = q1.x, sdz = q1.y, rdx = q1.z, rdy = q1.w;
    float rdz = q2.x, amin = q2.y, amax = q2.z, rlen = q2.w;
    float sdyE = q3.x, syE = q3.y, sdzE = q3.z, szE = q3.w;

    float spx = spacing[0], spy = spacing[1], spz = spacing[2];

    float acc = 0.f;

    if (amax > amin) {
        float range = amax - amin;
        constexpr float inv = 1.0f / (float)TPR;
        float lo = fmaf(range, (float)part * inv, amin);
        float hi = (part == TPR - 1) ? INFINITY
                                     : fmaf(range, (float)(part + 1) * inv, amin);
        float end = fminf(hi, amax);

        int ix, iy, iz, dix, diy, diz;
        float nxx, nxy, nxz;

        // first plane crossing with alpha >= lo per axis (guards kept here)
        #define SETUP(SP, SRC, SDD, RD, I, DI, NXT)                                \
        {                                                                          \
            float q = fmaf(lo, SDD, SRC) / (SP);                                   \
            q = fminf(fmaxf(q, -1.f), 257.f);                                      \
            if ((SDD) > 0.f) {                                                     \
                DI = 1;                                                            \
                I = (int)ceilf(q);                                                 \
                while (I > 0 && palpha(I - 1, SP, SRC, RD) >= lo) --I;             \
                while (I <= NPLANE && palpha(I, SP, SRC, RD) < lo) ++I;            \
                NXT = (I <= NPLANE) ? palpha(I, SP, SRC, RD) : INFINITY;           \
            } else {                                                               \
                DI = -1;                                                           \
                I = (int)floorf(q);                                                \
                while (I < NPLANE && palpha(I + 1, SP, SRC, RD) >= lo) ++I;        \
                while (I >= 0 && palpha(I, SP, SRC, RD) < lo) --I;                 \
                NXT = (I >= 0) ? palpha(I, SP, SRC, RD) : INFINITY;                \
            }                                                                      \
        }

        SETUP(spx, sx, sdx, rdx, ix, dix, nxx)
        SETUP(spy, sy, sdy, rdy, iy, diy, nxy)
        SETUP(spz, sz, sdz, rdz, iz, diz, nxz)
        #undef SETUP

        float fiy = (float)iy, fiz = (float)iz;
        float dfy = (float)diy, dfz = (float)diz;
        float nsy = -sy, nsz = -sz;
        int offcx = (dix > 0) ? -1 : 0;        // x-cell = ix + offcx

        #define ADV()                                                              \
            if (nxx == cur) { ix += dix; nxx = palpha(ix, spx, sx, rdx); }         \
            if (nxy == cur) { fiy += dfy; nxy = palpha_f(fiy, spy, nsy, rdy); }    \
            if (nxz == cur) { fiz += dfz; nxz = palpha_f(fiz, spz, nsz, rdz); }

        #define SEG_ADDR(CUR, E, ADDR)                                             \
        {                                                                          \
            float amid = 0.5f * ((CUR) + (E));                                     \
            float pyv = fmaf(amid, sdyE, syE);                                     \
            float pzv = fmaf(amid, sdzE, szE);                                     \
            int jx = ix + offcx; jx = jx < 0 ? 0 : (jx > 255 ? 255 : jx);          \
            int jy = (int)pyv;   jy = jy < 0 ? 0 : (jy > 255 ? 255 : jy);          \
            int jz = (int)pzv;   jz = jz < 0 ? 0 : (jz > 255 ? 255 : jz);          \
            ADDR = (jx << 16) + (jy << 8) + jz;                                    \
        }

        float cur = fminf(fminf(nxx, nxy), nxz);

        if (cur < end) {
            // peel: compute segment 0, issue its load
            ADV();
            float nxt = fminf(fminf(nxx, nxy), nxz);
            float e   = fminf(nxt, amax);
            int addr; SEG_ADDR(cur, e, addr)
            float pstep = e - cur;
            float pval  = vol[addr];
            cur = nxt;

            while (cur < end) {
                // advance to segment n+1, issue its load while load n in flight
                ADV();
                nxt = fminf(fminf(nxx, nxy), nxz);
                e   = fminf(nxt, amax);
                int addr2; SEG_ADDR(cur, e, addr2)
                float nval = vol[addr2];           // issue (vmcnt grows)
                acc = fmaf(pval, pstep, acc);      // consume load n (vmcnt(1))
                pval  = nval;
                pstep = e - cur;
                cur = nxt;
            }
            acc = fmaf(pval, pstep, acc);          // drain
        }
        #undef ADV
        #undef SEG_ADDR
    }

    // reduction: fold the wave's 4 partitions (lanes r, r+16, r+32, r+48),
    // then the block's 4 waves via a 64-float LDS tile.
    acc += __shfl_xor(acc, 16);
    acc += __shfl_xor(acc, 32);

    __shared__ float red[64];
    int wave = tid >> 6;                     // 0..3
    if ((tid & 63) < 16)
        red[(wave << 4) | rlo] = acc;
    __syncthreads();

    if (tid < 16) {
        float s = red[tid] + red[16 + tid] + red[32 + tid] + red[48 + tid];
        int tfast = *(const int*)(ws + (size_t)65536 * 16);
        int ti = tfast ? (rl & 255) : (rl >> 8);
        int si = tfast ? (rl >> 8) : (rl & 255);
        out[ti * 256 + si] = s * rlen;
    }
}

extern "C" void kernel_launch(void* const* d_in, const int* in_sizes, int n_in,
                              void* d_out, int out_size, void* d_ws, size_t ws_size,
                              hipStream_t stream) {
    const float* vol     = (const float*)d_in[0];
    const float* spacing = (const float*)d_in[1];
    const float* sdr     = (const float*)d_in[2];
    const float* rot     = (const float*)d_in[3];
    const float* trans   = (const float*)d_in[4];
    float* out = (float*)d_out;
    float* ws  = (float*)d_ws;

    ray_setup<<<256, 256, 0, stream>>>(spacing, sdr, rot, trans, ws);

    int nblocks = 256 * 256 / 16;   // 4096 blocks x 256 threads (16 rays each)
    drr_kernel<<<nblocks, 256, 0, stream>>>(vol, spacing, ws, out);
}

// Round 16
// 62.466 us; speedup vs baseline: 1.1108x; 1.1108x over previous
//
#include <hip/hip_runtime.h>
#include <math.h>

// DRR via Siddon ray tracing, 256^3 volume, 256x256 detector.
// R10 skeleton (best measured): block = 256 threads = 16 consecutive rays
// (lane-fast) x 16 alpha-partitions (slow); wave = 16 rays x 4 adjacent
// partitions; shfl_xor + 64-float LDS reduction. ONE change vs R10:
// center-out (longest-first) block ordering -- central detector blocks
// (longest rays) launch first, edge blocks (short/empty rays) backfill the
// drain tail (LPT scheduling). Consecutive launch indices still map to
// adjacent ti-chunks of the same si, preserving L1/L2 locality (unlike the
// R14 scatter, which regressed). Pure block-index permutation: per-ray
// arithmetic is bit-identical to R10 (absmax 0.5 proven).

#define NPLANE 256
constexpr int TPR = 16;

__device__ __forceinline__ float palpha(int i, float sp, float src, float rd) {
    return fmaf((float)i, sp, -src) * rd;
}

__global__ __launch_bounds__(256) void drr_kernel(
    const float* __restrict__ vol,
    const float* __restrict__ spacing,
    const float* __restrict__ sdrp,
    const float* __restrict__ rot,
    const float* __restrict__ trans,
    float* __restrict__ out)
{
    int tid  = threadIdx.x;
    int part = tid >> 4;                    // 0..15 (slow)
    int rlo  = tid & 15;                    // ray-in-block (fast)

    // ---- center-out (longest-first) block ordering ----
    // launch n = k*16 + j; si-order k and ti-chunk-order j both center-out.
    int b  = (int)blockIdx.x;
    int k  = b >> 4;                        // 0..255
    int j  = b & 15;                        // 0..15
    int sio = 127 + ((k & 1) ? ((k + 1) >> 1) : -(k >> 1));   // 127,128,126,...
    int tco = 7   + ((j & 1) ? ((j + 1) >> 1) : -(j >> 1));   // 7,8,6,9,...
    int g  = (sio << 4) | tco;              // ray-group id (bijective in 0..4095)
    int rl = (g << 4) | rlo;                // 0..65535 linear ray id

    // R = Rz(theta) @ Ry(phi) @ Rx(gamma): columns 0 (ray dir), 1 (u), 2 (v)
    float theta = rot[0], phi = rot[1], gam = rot[2];
    float ct = cosf(theta), st = sinf(theta);
    float cp = cosf(phi),   sp_ = sinf(phi);
    float cg = cosf(gam),   sg = sinf(gam);

    float r0x = ct * cp, r0y = st * cp, r0z = -sp_;
    float ux = ct * sp_ * sg - st * cg, uy = st * sp_ * sg + ct * cg, uz = cp * sg;
    float vx = ct * sp_ * cg + st * sg, vy = st * sp_ * cg - ct * sg, vz = cp * cg;

    // lane-fast detector axis = least stride-weighted volume motion (uniform)
    float cost_u = fabsf(ux) * 65536.f + fabsf(uy) * 256.f + fabsf(uz);
    float cost_v = fabsf(vx) * 65536.f + fabsf(vy) * 256.f + fabsf(vz);
    bool tfast = cost_u < cost_v;
    int ti = tfast ? (rl & 255) : (rl >> 8);
    int si = tfast ? (rl >> 8) : (rl & 255);

    float sdr = sdrp[0];
    float tx = trans[0], ty = trans[1], tz = trans[2];

    float sx = sdr * r0x + tx,  sy = sdr * r0y + ty,  sz = sdr * r0z + tz;
    float cxx = -sdr * r0x + tx, cxy = -sdr * r0y + ty, cxz = -sdr * r0z + tz;

    float tval = (float)(ti - 127) * 2.0f;
    float sval = (float)(si - 127) * 2.0f;

    float gx = tval * ux + sval * vx + cxx;
    float gy = tval * uy + sval * vy + cxy;
    float gz = tval * uz + sval * vz + cxz;

    float sdx = gx - sx + 1e-8f;
    float sdy = gy - sy + 1e-8f;
    float sdz = gz - sz + 1e-8f;

    float spx = spacing[0], spy = spacing[1], spz = spacing[2];
    float rdx = 1.0f / sdx, rdy = 1.0f / sdy, rdz = 1.0f / sdz;

    float a0x = palpha(0, spx, sx, rdx), a1x = palpha(NPLANE, spx, sx, rdx);
    float a0y = palpha(0, spy, sy, rdy), a1y = palpha(NPLANE, spy, sy, rdy);
    float a0z = palpha(0, spz, sz, rdz), a1z = palpha(NPLANE, spz, sz, rdz);

    float amin = fmaxf(fmaxf(fminf(a0x, a1x), fminf(a0y, a1y)), fminf(a0z, a1z));
    float amax = fminf(fminf(fmaxf(a0x, a1x), fmaxf(a0y, a1y)), fmaxf(a0z, a1z));

    float acc = 0.f;

    if (amax > amin) {
        float range = amax - amin;
        constexpr float inv = 1.0f / (float)TPR;
        float lo = fmaf(range, (float)part * inv, amin);
        float hi = (part == TPR - 1) ? INFINITY
                                     : fmaf(range, (float)(part + 1) * inv, amin);
        float end = fminf(hi, amax);

        int ix, iy, iz, dix, diy, diz;
        float nxx, nxy, nxz;

        // first plane crossing with alpha >= lo per axis
        #define SETUP(SP, SRC, SDD, RD, I, DI, NXT)                                \
        {                                                                          \
            float q = fmaf(lo, SDD, SRC) / (SP);                                   \
            q = fminf(fmaxf(q, -1.f), 257.f);                                      \
            if ((SDD) > 0.f) {                                                     \
                DI = 1;                                                            \
                I = (int)ceilf(q);                                                 \
                while (I > 0 && palpha(I - 1, SP, SRC, RD) >= lo) --I;             \
                while (I <= NPLANE && palpha(I, SP, SRC, RD) < lo) ++I;            \
                NXT = (I <= NPLANE) ? palpha(I, SP, SRC, RD) : INFINITY;           \
            } else {                                                               \
                DI = -1;                                                           \
                I = (int)floorf(q);                                                \
                while (I < NPLANE && palpha(I + 1, SP, SRC, RD) >= lo) ++I;        \
                while (I >= 0 && palpha(I, SP, SRC, RD) < lo) --I;                 \
                NXT = (I >= 0) ? palpha(I, SP, SRC, RD) : INFINITY;                \
            }                                                                      \
        }

        SETUP(spx, sx, sdx, rdx, ix, dix, nxx)
        SETUP(spy, sy, sdy, rdy, iy, diy, nxy)
        SETUP(spz, sz, sdz, rdz, iz, diz, nxz)
        #undef SETUP

        float ispx = 1.0f / spx, ispy = 1.0f / spy, ispz = 1.0f / spz;

        #define ADVANCE_MERGE()                                                    \
            if (nxx == cur) { ix += dix;                                           \
                nxx = ((unsigned)ix <= NPLANE) ? palpha(ix, spx, sx, rdx)          \
                                               : INFINITY; }                       \
            if (nxy == cur) { iy += diy;                                           \
                nxy = ((unsigned)iy <= NPLANE) ? palpha(iy, spy, sy, rdy)          \
                                               : INFINITY; }                       \
            if (nxz == cur) { iz += diz;                                           \
                nxz = ((unsigned)iz <= NPLANE) ? palpha(iz, spz, sz, rdz)          \
                                               : INFINITY; }

        #define SEG_ADDR(CUR, E, ADDR)                                             \
        {                                                                          \
            float amid = 0.5f * ((CUR) + (E));                                     \
            float pxv = fmaf(amid, sdx, sx) * ispx;                                \
            float pyv = fmaf(amid, sdy, sy) * ispy;                                \
            float pzv = fmaf(amid, sdz, sz) * ispz;                                \
            int jx = (int)pxv; jx = jx < 0 ? 0 : (jx > 255 ? 255 : jx);            \
            int jy = (int)pyv; jy = jy < 0 ? 0 : (jy > 255 ? 255 : jy);            \
            int jz = (int)pzv; jz = jz < 0 ? 0 : (jz > 255 ? 255 : jz);            \
            ADDR = (jx << 16) + (jy << 8) + jz;                                    \
        }

        float cur = fminf(fminf(nxx, nxy), nxz);

        if (cur < end) {
            // peel: compute segment 0, issue its load
            ADVANCE_MERGE();
            float nxt = fminf(fminf(nxx, nxy), nxz);
            float e   = fminf(nxt, amax);
            int addr; SEG_ADDR(cur, e, addr)
            float pstep = e - cur;
            float pval  = vol[addr];
            cur = nxt;

            while (cur < end) {
                // advance to segment n+1, issue its load while load n in flight
                ADVANCE_MERGE();
                nxt = fminf(fminf(nxx, nxy), nxz);
                e   = fminf(nxt, amax);
                int addr2; SEG_ADDR(cur, e, addr2)
                float nval = vol[addr2];           // issue (vmcnt grows)
                acc = fmaf(pval, pstep, acc);      // consume load n (vmcnt(1))
                pval  = nval;
                pstep = e - cur;
                cur = nxt;
            }
            acc = fmaf(pval, pstep, acc);          // drain
        }
        #undef ADVANCE_MERGE
        #undef SEG_ADDR
    }

    // reduction: fold the wave's 4 partitions (lanes r, r+16, r+32, r+48),
    // then the block's 4 waves via a 64-float LDS tile.
    acc += __shfl_xor(acc, 16);
    acc += __shfl_xor(acc, 32);

    __shared__ float red[64];
    int wave = tid >> 6;                     // 0..3
    if ((tid & 63) < 16)
        red[(wave << 4) | rlo] = acc;
    __syncthreads();

    if (tid < 16) {
        float s = red[tid] + red[16 + tid] + red[32 + tid] + red[48 + tid];
        float rl2 = sqrtf(sdx * sdx + sdy * sdy + sdz * sdz);
        out[ti * 256 + si] = s * rl2;
    }
}

extern "C" void kernel_launch(void* const* d_in, const int* in_sizes, int n_in,
                              void* d_out, int out_size, void* d_ws, size_t ws_size,
                              hipStream_t stream) {
    const float* vol     = (const float*)d_in[0];
    const float* spacing = (const float*)d_in[1];
    const float* sdr     = (const float*)d_in[2];
    const float* rot     = (const float*)d_in[3];
    const float* trans   = (const float*)d_in[4];
    float* out = (float*)d_out;

    int nblocks = 256 * 256 / 16;   // 4096 blocks x 256 threads (16 rays each)
    drr_kernel<<<nblocks, 256, 0, stream>>>(vol, spacing, sdr, rot, trans, out);
}